// Round 5
// baseline (199.241 us; speedup 1.0000x reference)
//
#include <hip/hip_runtime.h>

// Circuit_67473936220746, round 10: de-fuse into two streaming GEMM kernels.
// MID is staged in GLOBAL memory, pre-split bf16 h/l in frag-linear layout,
// and lives inside d_out: the h-slice of MID (Mh 64KB + Ml 64KB) occupies
// exactly the h-slice of the final output (ch0 chunk + ch1 chunk). K2 reads
// only its own slice, barriers, then overwrites it.
//
//   K1 midK: 512 blocks x 512 thr, 64KB LDS (one ch at a time, DMA-staged,
//            source-side XOR swizzle) -> 2 blocks/CU, cross-block overlap.
//            mid[kp][b] = sum_{ch,a} WA[kp][ch*128+a] * T[ch][b][a]
//            written as bf16 h/l (tsplit) in K2's A-fragment frag-linear order.
//   K2 outK: 512 blocks x 512 thr, NO LDS. A-frags load directly from MID
//            (coalesced 16B/lane), B = WB frags. One barrier before epilogue.
//            out[ch''][kb][ka] = sum_{ch',b} WB[ch''*128+kb][ch'*128+b] * mid[.][b]
//
// WA = (W2*W1)*W0 (fp32 on device), WB = W3, Wg = [[Ui,Ur],[Ur,-Ui]].
// 3-term bf16 split both passes (ah*bh + al*bh + ah*bl); per-element
// accumulation order identical to the fused kernels (bit-identical numerics).
//
// MFMA 16x16x32 bf16 layouts (HW-verified):
//   A: m = lane&15, k = (lane>>4)*8 + j (16B/lane contiguous)
//   B: n = lane&15, k = (lane>>4)*8 + j
//   C/D: col(n) = lane&15, row(m) = (lane>>4)*4 + reg
//
// Frag-linear storage: frag(tile,ks) = 64 slots x 8 shorts; a lane reads its
// 16B at frag*1024 + lane*16. MID global layout = fragOff(ka, k2) per h-slice
// (verified identical to the K1 write formula below).

typedef __attribute__((ext_vector_type(8))) short bf16x8;
typedef __attribute__((ext_vector_type(4))) short bf16x4;
typedef __attribute__((ext_vector_type(4))) float f32x4;

static constexpr int NSTATE = 1 << 23;

// truncation split: x ~= bf16(h) + bf16(l), rel err ~2^-16
__device__ inline void tsplit(float x, unsigned short& h, unsigned short& l) {
    unsigned int u = __float_as_uint(x);
    h = (unsigned short)(u >> 16);
    float hf = __uint_as_float(u & 0xFFFF0000u);
    l = (unsigned short)(__float_as_uint(x - hf) >> 16);
}

__device__ inline void split8(const float* xv, bf16x8& hv, bf16x8& lv) {
    #pragma unroll
    for (int i = 0; i < 8; ++i) {
        unsigned short h, l;
        tsplit(xv[i], h, l);
        hv[i] = (short)h; lv[i] = (short)l;
    }
}

// RNE split (weights, prep only)
__device__ inline void rsplit(float x, unsigned short& h, unsigned short& l) {
    unsigned int u = __float_as_uint(x);
    unsigned int r = (u + 0x7FFFu + ((u >> 16) & 1u)) >> 16;
    h = (unsigned short)r;
    float hf = __uint_as_float(r << 16);
    unsigned int u2 = __float_as_uint(x - hf);
    l = (unsigned short)((u2 + 0x7FFFu + ((u2 >> 16) & 1u)) >> 16);
}

// signed block-matrix element: Wg[kp][ap], Ug -> U[g][0][0][0]
__device__ inline float wElem(const float* __restrict__ Ug, int kp, int ap) {
    const int co = kp >> 7, ci = ap >> 7;
    const float v = Ug[((co == ci) ? 16384 : 0) + (kp & 127) * 128 + (ap & 127)];
    return (co & ci) ? -v : v;
}

// frag-linear scatter offset (in shorts) for element (row i, col t) of a 256x256 W
__device__ inline int fragOff(int i, int t) {
    const int frag = (i >> 4) * 8 + (t >> 5);
    const int slot = (i & 15) + 16 * ((t >> 3) & 3);
    return frag * 512 + slot * 8 + (t & 7);
}

// async 16B/lane global -> LDS (lds dest = wave-uniform base + lane*16)
__device__ inline void dma16(const float* gp, float* lp) {
    __builtin_amdgcn_global_load_lds(
        (const __attribute__((address_space(1))) unsigned int*)gp,
        (__attribute__((address_space(3))) unsigned int*)lp,
        16, 0, 0);
}

// ---- single prep launch ----
// blocks 0..255:  WA row i = ((W2*W1)*W0)[i], rsplit + frag scatter
// blocks 256..511: WB row i = W3g[i], rsplit + frag scatter
__global__ __launch_bounds__(256)
void prep_all(const float* __restrict__ U,
              unsigned short* __restrict__ WAh, unsigned short* __restrict__ WAl,
              unsigned short* __restrict__ WBh, unsigned short* __restrict__ WBl) {
    __shared__ float Arow[256];
    const int t = threadIdx.x;
    if (blockIdx.x < 256) {
        const int i = blockIdx.x;
        Arow[t] = wElem(U + 2 * 32768, i, t);               // W2 row i
        __syncthreads();
        float r = 0.f;
        #pragma unroll 8
        for (int k = 0; k < 256; ++k)
            r = fmaf(Arow[k], wElem(U + 32768, k, t), r);   // (W2*W1)[i][t]
        __syncthreads();
        Arow[t] = r;
        __syncthreads();
        float s = 0.f;
        #pragma unroll 8
        for (int k = 0; k < 256; ++k)
            s = fmaf(Arow[k], wElem(U, k, t), s);           // * W0
        unsigned short h, l;
        rsplit(s, h, l);
        const int off = fragOff(i, t);
        WAh[off] = h; WAl[off] = l;
    } else {
        const int i = blockIdx.x - 256;
        unsigned short h, l;
        rsplit(wElem(U + 3 * 32768, i, t), h, l);
        const int off = fragOff(i, t);
        WBh[off] = h; WBl[off] = l;
    }
}

// ---- K1: state -> MID (bf16 h/l frag-linear, stored in dst slices) ----
// 512 blocks (h) x 512 threads (8 waves, mg2 x ng4), 64 KB LDS, 2 blocks/CU.
__global__ __launch_bounds__(512, 4)
void midK(const float* __restrict__ src, float* __restrict__ dst,
          const unsigned short* __restrict__ WAh, const unsigned short* __restrict__ WAl)
{
    __shared__ float Sf[16384];   // 64 KB: one ch of state (128 rows x 512 B)

    const int t    = threadIdx.x;
    const int lane = t & 63;
    const int w    = t >> 6;            // 0..7
    const int col  = lane & 15, quad = lane >> 4;
    const int mg   = w & 1;             // m-group (2): b-tiles
    const int ng   = w >> 1;            // n-group (4): kp-tiles
    const size_t hbase = (size_t)blockIdx.x * 16384;

    unsigned short* MhG = (unsigned short*)(dst + hbase);                    // 64 KB chunk (ch0 slice)
    unsigned short* MlG = (unsigned short*)(dst + (size_t)NSTATE + hbase);   // 64 KB chunk (ch1 slice)

    f32x4 acc[4][4];
    #pragma unroll
    for (int mi = 0; mi < 4; ++mi)
        #pragma unroll
        for (int nj = 0; nj < 4; ++nj) acc[mi][nj] = (f32x4)0.f;

    #pragma unroll
    for (int half = 0; half < 2; ++half) {
        if (half) __syncthreads();      // all ch0 reads done before overwrite
        // ---- stage ch=half: DMA fp32, source-side XOR swizzle, linear LDS ----
        // wave w covers rows w*16..w*16+15; 1 KB (2 rows) per instr.
        #pragma unroll
        for (int j = 0; j < 8; ++j) {
            const int r0 = w * 16 + j * 2;
            const int r  = r0 + (lane >> 5);
            const int cb = ((lane & 31) << 4) ^ ((r & 7) << 4);
            dma16(src + (size_t)half * NSTATE + hbase + (size_t)r * 128 + (cb >> 2),
                  Sf + r0 * 128);
        }
        __syncthreads();

        #pragma unroll
        for (int ks4 = 0; ks4 < 4; ++ks4) {
            const int ks = half * 4 + ks4;
            bf16x8 bh[4], bl[4];
            #pragma unroll
            for (int nj = 0; nj < 4; ++nj) {
                const int fo = ((ng * 4 + nj) * 8 + ks) * 512 + lane * 8;
                bh[nj] = *(const bf16x8*)(WAh + fo);
                bl[nj] = *(const bf16x8*)(WAl + fo);
            }
            const int cb0 = ks4 * 128 + quad * 32;
            #pragma unroll
            for (int mi = 0; mi < 4; ++mi) {
                const int r   = (mg * 4 + mi) * 16 + col;
                const int swz = (r & 7) << 4;
                const char* rowp = (const char*)Sf + r * 512;
                float xv[8];
                *(float4*)&xv[0] = *(const float4*)(rowp + (cb0 ^ swz));
                *(float4*)&xv[4] = *(const float4*)(rowp + ((cb0 + 16) ^ swz));
                bf16x8 ah, al;
                split8(xv, ah, al);
                // term-major per mi: same per-element order as fused (t1,t2,t3)
                #pragma unroll
                for (int nj = 0; nj < 4; ++nj)
                    acc[mi][nj] = __builtin_amdgcn_mfma_f32_16x16x32_bf16(ah, bh[nj], acc[mi][nj], 0, 0, 0);
                #pragma unroll
                for (int nj = 0; nj < 4; ++nj)
                    acc[mi][nj] = __builtin_amdgcn_mfma_f32_16x16x32_bf16(al, bh[nj], acc[mi][nj], 0, 0, 0);
                #pragma unroll
                for (int nj = 0; nj < 4; ++nj)
                    acc[mi][nj] = __builtin_amdgcn_mfma_f32_16x16x32_bf16(ah, bl[nj], acc[mi][nj], 0, 0, 0);
            }
        }
    }

    // ---- MID write: element (b = mt*16+quad*4+r, kp = nt*16+col) ----
    //   = MID A-frag layout fragOff(ka = kp&127, k2 = (kp>>7)*128 + b):
    //   frag = (nt&7)*8 + (nt>>3)*4 + (mt>>1); slot = col + 16*((mt*2+(quad>>1))&3);
    //   short-offset = (quad&1)*4 + r.  Wave writes 512 B contiguous per (mi,nj).
    #pragma unroll
    for (int mi = 0; mi < 4; ++mi) {
        const int mt  = mg * 4 + mi;
        const int oct = (mt * 2 + (quad >> 1)) & 3;
        #pragma unroll
        for (int nj = 0; nj < 4; ++nj) {
            const int nt   = ng * 4 + nj;
            const int frag = (nt & 7) * 8 + (nt >> 3) * 4 + (mt >> 1);
            const int soff = frag * 512 + (col + 16 * oct) * 8 + (quad & 1) * 4;
            unsigned short hh[4], ll[4];
            #pragma unroll
            for (int r = 0; r < 4; ++r) tsplit(acc[mi][nj][r], hh[r], ll[r]);
            bf16x4 hv = { (short)hh[0], (short)hh[1], (short)hh[2], (short)hh[3] };
            bf16x4 lv = { (short)ll[0], (short)ll[1], (short)ll[2], (short)ll[3] };
            *(bf16x4*)(MhG + soff) = hv;
            *(bf16x4*)(MlG + soff) = lv;
        }
    }
}

// ---- K2: MID -> out. 512 blocks (h) x 512 threads, NO LDS, one barrier ----
// A-frags (MID) load directly from dst slices (coalesced 1KB/wave/instr);
// after the k-loop all MID reads are complete -> barrier -> overwrite slice.
__global__ __launch_bounds__(512, 4)
void outK(float* __restrict__ dst,
          const unsigned short* __restrict__ WBh, const unsigned short* __restrict__ WBl)
{
    const int t    = threadIdx.x;
    const int lane = t & 63;
    const int w    = t >> 6;            // 0..7
    const int col  = lane & 15, quad = lane >> 4;
    const int mg   = w & 1;             // m-group (2): ka-tiles
    const int ng   = w >> 1;            // n-group (4): kp2-tiles
    const size_t hbase = (size_t)blockIdx.x * 16384;

    const unsigned short* MhG = (const unsigned short*)(dst + hbase);
    const unsigned short* MlG = (const unsigned short*)(dst + (size_t)NSTATE + hbase);

    f32x4 acc2[4][4];
    #pragma unroll
    for (int mi = 0; mi < 4; ++mi)
        #pragma unroll
        for (int nj = 0; nj < 4; ++nj) acc2[mi][nj] = (f32x4)0.f;

    #pragma unroll
    for (int ks2 = 0; ks2 < 8; ++ks2) {
        bf16x8 bh[4], bl[4];
        #pragma unroll
        for (int nj = 0; nj < 4; ++nj) {
            const int fo = ((ng * 4 + nj) * 8 + ks2) * 512 + lane * 8;
            bh[nj] = *(const bf16x8*)(WBh + fo);
            bl[nj] = *(const bf16x8*)(WBl + fo);
        }
        #pragma unroll
        for (int mi = 0; mi < 4; ++mi) {
            const int fo = ((mg * 4 + mi) * 8 + ks2) * 512 + lane * 8;
            const bf16x8 a2h = *(const bf16x8*)(MhG + fo);
            const bf16x8 a2l = *(const bf16x8*)(MlG + fo);
            #pragma unroll
            for (int nj = 0; nj < 4; ++nj)
                acc2[mi][nj] = __builtin_amdgcn_mfma_f32_16x16x32_bf16(a2h, bh[nj], acc2[mi][nj], 0, 0, 0);
            #pragma unroll
            for (int nj = 0; nj < 4; ++nj)
                acc2[mi][nj] = __builtin_amdgcn_mfma_f32_16x16x32_bf16(a2l, bh[nj], acc2[mi][nj], 0, 0, 0);
            #pragma unroll
            for (int nj = 0; nj < 4; ++nj)
                acc2[mi][nj] = __builtin_amdgcn_mfma_f32_16x16x32_bf16(a2h, bl[nj], acc2[mi][nj], 0, 0, 0);
        }
    }

    __syncthreads();    // every wave's MID reads complete before slice overwrite

    // ---- epilogue: out[ch''][kb][ka], float4 over ka (coalesced) ----
    #pragma unroll
    for (int nj = 0; nj < 4; ++nj) {
        const int kp2  = (ng * 4 + nj) * 16 + col;
        const int chpp = kp2 >> 7, kb = kp2 & 127;
        float* o = dst + (size_t)chpp * NSTATE + hbase + (size_t)kb * 128;
        #pragma unroll
        for (int mi = 0; mi < 4; ++mi) {
            const int ka = (mg * 4 + mi) * 16 + quad * 4;
            *(float4*)(o + ka) = *(float4*)&acc2[mi][nj];
        }
    }
}

extern "C" void kernel_launch(void* const* d_in, const int* in_sizes, int n_in,
                              void* d_out, int out_size, void* d_ws, size_t ws_size,
                              hipStream_t stream) {
    const float* state = (const float*)d_in[0];   // (2, 2^23)
    const float* U     = (const float*)d_in[1];   // (4, 2, 128, 128)
    float* out = (float*)d_out;

    // ws: WAh WAl WBh WBl (128 KB each, frag-linear bf16)
    unsigned short* WAh = (unsigned short*)d_ws;
    unsigned short* WAl = WAh + 65536;
    unsigned short* WBh = WAh + 2 * 65536;
    unsigned short* WBl = WAh + 3 * 65536;

    prep_all<<<512, 256, 0, stream>>>(U, WAh, WAl, WBh, WBl);
    midK<<<512, 512, 0, stream>>>(state, out, WAh, WAl);
    outK<<<512, 512, 0, stream>>>(out, WBh, WBl);
}

// Round 6
// 166.826 us; speedup vs baseline: 1.1943x; 1.1943x over previous
//
#include <hip/hip_runtime.h>

// Circuit_67473936220746, round 11: re-fused, block = (h, ka-half), 512 thr
// (8 waves), 64 KB LDS -> 2 blocks/CU. State staged in 4 chunks (ch, a-half)
// of 32 KB, pre-split bf16 h/l at stage time, two ping-pong buffers; chunk
// loads go global->REG one phase early (regs stay in flight across barriers),
// split+ds_write just before the consuming phase. MID (64 KB) aliases both
// buffers after pass A. mg=1 geometry both passes (acc[8] / acc2[4][2]):
// every W fragment is read exactly once per block (L2 W traffic ~3x lower
// than fused6). State is read twice across the grid (once per ka-half) but
// is L3-resident. Numerics bit-identical to rounds 5-10.
//
// State per high-index h (bits 14-22): T[ch][b][a] (b = bits 7-13, a = bits 0-6).
//   Pass A: mid[kp=ch'*128+ka][b] = sum_{ch,a} WA[kp][ch*128+a] * T[ch][b][a]
//   Pass B: out[ch''][kb][ka]     = sum_{ch',b} WB[ch''*128+kb][ch'*128+b] * mid[ch'*128+ka][b]
// WA = (W2*W1)*W0 (fp32 on device), WB = W3, Wg = [[Ui,Ur],[Ur,-Ui]].
// 3-term bf16 split both passes (ah*bh + al*bh + ah*bl).
//
// MFMA 16x16x32 bf16 layouts (HW-verified):
//   A: m = lane&15, k = (lane>>4)*8 + j (16B/lane contiguous)
//   B: n = lane&15, k = (lane>>4)*8 + j
//   C/D: col(n) = lane&15, row(m) = (lane>>4)*4 + reg
//
// Frag-linear: frag = 64 slots x 8 shorts, lane reads 16B at
// frag*1024 + slotSwz(frag,lane)*16. Chunk buffers: 16 frags (8 b-tiles x
// 2 ks) of h + same of l. MID: 32 frags (4 ka-tiles x 8 ks2) h + l.

typedef __attribute__((ext_vector_type(8))) short bf16x8;
typedef __attribute__((ext_vector_type(4))) short bf16x4;
typedef __attribute__((ext_vector_type(4))) float f32x4;

static constexpr int NSTATE = 1 << 23;

// truncation split: x ~= bf16(h) + bf16(l), rel err ~2^-16
__device__ inline void tsplit(float x, unsigned short& h, unsigned short& l) {
    unsigned int u = __float_as_uint(x);
    h = (unsigned short)(u >> 16);
    float hf = __uint_as_float(u & 0xFFFF0000u);
    l = (unsigned short)(__float_as_uint(x - hf) >> 16);
}

// RNE split (weights, prep only)
__device__ inline void rsplit(float x, unsigned short& h, unsigned short& l) {
    unsigned int u = __float_as_uint(x);
    unsigned int r = (u + 0x7FFFu + ((u >> 16) & 1u)) >> 16;
    h = (unsigned short)r;
    float hf = __uint_as_float(r << 16);
    unsigned int u2 = __float_as_uint(x - hf);
    l = (unsigned short)((u2 + 0x7FFFu + ((u2 >> 16) & 1u)) >> 16);
}

// signed block-matrix element: Wg[kp][ap], Ug -> U[g][0][0][0]
__device__ inline float wElem(const float* __restrict__ Ug, int kp, int ap) {
    const int co = kp >> 7, ci = ap >> 7;
    const float v = Ug[((co == ci) ? 16384 : 0) + (kp & 127) * 128 + (ap & 127)];
    return (co & ci) ? -v : v;
}

// frag-linear scatter offset (in shorts) for element (row i, col t) of a 256x256 W
__device__ inline int fragOff(int i, int t) {
    const int frag = (i >> 4) * 8 + (t >> 5);
    const int slot = (i & 15) + 16 * ((t >> 3) & 3);
    return frag * 512 + slot * 8 + (t & 7);
}

// LDS slot swizzle (involution per frag): spreads slot bits 4-5 into banks
__device__ inline int slotSwz(int frag, int slot) {
    return slot ^ ((slot >> 3) & 6) ^ (frag & 7);
}

// ---- single prep launch ----
// blocks 0..255:  WA row i = ((W2*W1)*W0)[i], rsplit + frag scatter
// blocks 256..511: WB row i = W3g[i], rsplit + frag scatter
__global__ __launch_bounds__(256)
void prep_all(const float* __restrict__ U,
              unsigned short* __restrict__ WAh, unsigned short* __restrict__ WAl,
              unsigned short* __restrict__ WBh, unsigned short* __restrict__ WBl) {
    __shared__ float Arow[256];
    const int t = threadIdx.x;
    if (blockIdx.x < 256) {
        const int i = blockIdx.x;
        Arow[t] = wElem(U + 2 * 32768, i, t);               // W2 row i
        __syncthreads();
        float r = 0.f;
        #pragma unroll 8
        for (int k = 0; k < 256; ++k)
            r = fmaf(Arow[k], wElem(U + 32768, k, t), r);   // (W2*W1)[i][t]
        __syncthreads();
        Arow[t] = r;
        __syncthreads();
        float s = 0.f;
        #pragma unroll 8
        for (int k = 0; k < 256; ++k)
            s = fmaf(Arow[k], wElem(U, k, t), s);           // * W0
        unsigned short h, l;
        rsplit(s, h, l);
        const int off = fragOff(i, t);
        WAh[off] = h; WAl[off] = l;
    } else {
        const int i = blockIdx.x - 256;
        unsigned short h, l;
        rsplit(wElem(U + 3 * 32768, i, t), h, l);
        const int off = fragOff(i, t);
        WBh[off] = h; WBl[off] = l;
    }
}

// ---- fused main: 1024 blocks (512 h x 2 ka-halves) x 512 threads ----
__global__ __launch_bounds__(512, 4)
void fused7(const float* __restrict__ src, float* __restrict__ dst,
            const unsigned short* __restrict__ WAh, const unsigned short* __restrict__ WAl,
            const unsigned short* __restrict__ WBh, const unsigned short* __restrict__ WBl)
{
    // 64 KB. Pass A: two 32 KB chunk buffers, each = 16 frags h (8192 shorts)
    // + 16 frags l. Pass B: Mh = shorts[0..16383], Ml = [16384..32767].
    __shared__ unsigned short S[32768];

    const int t    = threadIdx.x;
    const int lane = t & 63;
    const int w    = t >> 6;            // 0..7
    const int col  = lane & 15, quad = lane >> 4;
    const int hidx = blockIdx.x >> 1;
    const int ka0  = (blockIdx.x & 1) * 64;
    const size_t hbase = (size_t)hidx * 16384;

    // staging: thread t owns (b = t>>2, aLocal = (t&3)*16 .. +15) of each chunk
    const int sb = t >> 2;
    const int sa = (t & 3) * 16;

    // chunk q = (ch = q>>1, aHalf = q&1); holds ks = 2q, 2q+1
    auto ldChunk = [&](int q, float4* v) {
        const float* p = src + (size_t)(q >> 1) * NSTATE + hbase
                       + (size_t)sb * 128 + (q & 1) * 64 + sa;
        #pragma unroll
        for (int i = 0; i < 4; ++i) v[i] = *(const float4*)(p + i * 4);
    };
    auto stChunk = [&](int q, const float4* v) {
        const int bufH = (q & 1) * 16384;
        #pragma unroll
        for (int g = 0; g < 2; ++g) {
            const int aL = sa + g * 8;
            float f[8];
            *(float4*)&f[0] = v[g * 2];
            *(float4*)&f[4] = v[g * 2 + 1];
            bf16x8 hv, lv;
            #pragma unroll
            for (int i = 0; i < 8; ++i) {
                unsigned short h, l;
                tsplit(f[i], h, l);
                hv[i] = (short)h; lv[i] = (short)l;
            }
            const int frag = (sb >> 4) * 2 + (aL >> 5);     // b-tile*2 + ksc
            const int slot = (sb & 15) + 16 * ((aL & 31) >> 3);
            const int off  = bufH + frag * 512 + slotSwz(frag, slot) * 8;
            *(bf16x8*)&S[off] = hv;
            *(bf16x8*)&S[off + 8192] = lv;
        }
    };

    // ============ PASS A ============
    // m = b: 8 tiles, ALL owned by each wave (mg=1). n = kp-half: 8 tiles,
    // wave w owns tile w. Each W frag read exactly once per block.
    f32x4 acc[8];
    #pragma unroll
    for (int mi = 0; mi < 8; ++mi) acc[mi] = (f32x4)0.f;

    const int kptile = (w >> 2) * 8 + (ka0 >> 4) + (w & 3); // global kp tile

    float4 stA[4], stB[4];
    ldChunk(0, stA);
    stChunk(0, stA);
    ldChunk(1, stB);
    __syncthreads();                    // chunk 0 visible

    #pragma unroll
    for (int q = 0; q < 4; ++q) {
        const int bufH = (q & 1) * 16384;
        #pragma unroll
        for (int ksc = 0; ksc < 2; ++ksc) {
            const int ks = q * 2 + ksc;
            const int fw = (kptile * 8 + ks) * 512 + lane * 8;
            const bf16x8 bh = *(const bf16x8*)(WAh + fw);
            const bf16x8 bl = *(const bf16x8*)(WAl + fw);
            #pragma unroll
            for (int mi = 0; mi < 8; ++mi) {
                const int frag = mi * 2 + ksc;
                const int fo = bufH + frag * 512 + slotSwz(frag, lane) * 8;
                const bf16x8 ah = *(const bf16x8*)&S[fo];
                const bf16x8 al = *(const bf16x8*)&S[fo + 8192];
                acc[mi] = __builtin_amdgcn_mfma_f32_16x16x32_bf16(ah, bh, acc[mi], 0, 0, 0);
                acc[mi] = __builtin_amdgcn_mfma_f32_16x16x32_bf16(al, bh, acc[mi], 0, 0, 0);
                acc[mi] = __builtin_amdgcn_mfma_f32_16x16x32_bf16(ah, bl, acc[mi], 0, 0, 0);
            }
        }
        // pipeline: issue load q+2, write q+1 (regs arrived a phase ago)
        if (q == 0) { ldChunk(2, stA); stChunk(1, stB); }
        else if (q == 1) { ldChunk(3, stB); stChunk(2, stA); }
        else if (q == 2) { stChunk(3, stB); }
        __syncthreads();   // q<3: chunk q+1 visible & phase-q reads done;
                           // q==3: all A-reads done before MID alias write
    }

    // ---- MID write (aliases chunk buffers) ----
    // element (b = mi*16 + quad*4 + r, kp-local = w*16 + col):
    //   frag2 = (w&3)*8 + (w>>2)*4 + (mi>>1); slot = col + 16*((mi*2+(quad>>1))&3);
    //   short-offset = (quad&1)*4 + r
    #pragma unroll
    for (int mi = 0; mi < 8; ++mi) {
        const int oct   = (mi * 2 + (quad >> 1)) & 3;
        const int frag2 = (w & 3) * 8 + (w >> 2) * 4 + (mi >> 1);
        const int soff  = frag2 * 512 + slotSwz(frag2, col + 16 * oct) * 8 + (quad & 1) * 4;
        unsigned short hh[4], ll[4];
        #pragma unroll
        for (int r = 0; r < 4; ++r) tsplit(acc[mi][r], hh[r], ll[r]);
        bf16x4 hv = { (short)hh[0], (short)hh[1], (short)hh[2], (short)hh[3] };
        bf16x4 lv = { (short)ll[0], (short)ll[1], (short)ll[2], (short)ll[3] };
        *(bf16x4*)&S[soff] = hv;            // Mh
        *(bf16x4*)&S[16384 + soff] = lv;    // Ml
    }
    __syncthreads();

    // ============ PASS B ============
    // m2 = ka-half: 4 tiles, ALL owned by each wave (mg=1). n2 = kp2: 16
    // tiles, wave w owns tiles w*2, w*2+1. WB frags read once per block.
    f32x4 acc2[4][2];
    #pragma unroll
    for (int mi = 0; mi < 4; ++mi)
        #pragma unroll
        for (int nj = 0; nj < 2; ++nj) acc2[mi][nj] = (f32x4)0.f;

    #pragma unroll
    for (int ks2 = 0; ks2 < 8; ++ks2) {
        bf16x8 a2h[4], a2l[4];
        #pragma unroll
        for (int mi = 0; mi < 4; ++mi) {
            const int frag = mi * 8 + ks2;
            const int fo = frag * 512 + slotSwz(frag, lane) * 8;
            a2h[mi] = *(const bf16x8*)&S[fo];
            a2l[mi] = *(const bf16x8*)&S[16384 + fo];
        }
        #pragma unroll
        for (int nj = 0; nj < 2; ++nj) {
            const int fo = ((w * 2 + nj) * 8 + ks2) * 512 + lane * 8;
            const bf16x8 bh2 = *(const bf16x8*)(WBh + fo);
            const bf16x8 bl2 = *(const bf16x8*)(WBl + fo);
            #pragma unroll
            for (int mi = 0; mi < 4; ++mi) {
                acc2[mi][nj] = __builtin_amdgcn_mfma_f32_16x16x32_bf16(a2h[mi], bh2, acc2[mi][nj], 0, 0, 0);
                acc2[mi][nj] = __builtin_amdgcn_mfma_f32_16x16x32_bf16(a2l[mi], bh2, acc2[mi][nj], 0, 0, 0);
                acc2[mi][nj] = __builtin_amdgcn_mfma_f32_16x16x32_bf16(a2h[mi], bl2, acc2[mi][nj], 0, 0, 0);
            }
        }
    }

    // ---- epilogue: out[ch''][kb][ka0 + ka_loc], float4 over ka (coalesced) ----
    #pragma unroll
    for (int nj = 0; nj < 2; ++nj) {
        const int nt2  = w * 2 + nj;
        const int chpp = nt2 >> 3, kb = (nt2 & 7) * 16 + col;
        float* o = dst + (size_t)chpp * NSTATE + hbase + (size_t)kb * 128 + ka0;
        #pragma unroll
        for (int mi = 0; mi < 4; ++mi)
            *(float4*)(o + mi * 16 + quad * 4) = *(float4*)&acc2[mi][nj];
    }
}

extern "C" void kernel_launch(void* const* d_in, const int* in_sizes, int n_in,
                              void* d_out, int out_size, void* d_ws, size_t ws_size,
                              hipStream_t stream) {
    const float* state = (const float*)d_in[0];   // (2, 2^23)
    const float* U     = (const float*)d_in[1];   // (4, 2, 128, 128)
    float* out = (float*)d_out;

    // ws: WAh WAl WBh WBl (128 KB each, frag-linear bf16)
    unsigned short* WAh = (unsigned short*)d_ws;
    unsigned short* WAl = WAh + 65536;
    unsigned short* WBh = WAh + 2 * 65536;
    unsigned short* WBl = WAh + 3 * 65536;

    prep_all<<<512, 256, 0, stream>>>(U, WAh, WAl, WBh, WBl);
    fused7 <<<1024, 512, 0, stream>>>(state, out, WAh, WAl, WBh, WBl);
}

// Round 7
// 159.485 us; speedup vs baseline: 1.2493x; 1.0460x over previous
//
#include <hip/hip_runtime.h>

// Circuit_67473936220746, round 12: fused7 skeleton (block = (h, ka-half),
// 512 thr, 64 KB LDS, 2 blocks/CU, chunked ping-pong staging, read-once W)
// + explicit latency engineering:
//   * W-operand register double-buffer at distance 2 in BOTH passes
//   * cross-barrier W prefetch (pass-B ks2=0,1 issued before the MID barrier;
//     pass-A ks=0,1 issued in the prologue under the state DMA)
//   * load-before-store staging prologue (chunk1 + W fly during stChunk(0))
//   * A-frags batched 4-at-a-time before their 12 MFMAs
//   * XCD-chunked blockIdx swizzle (both ka-halves of an h + 64 consecutive
//     h per XCD -> state re-read is L2-hot)
// All index formulas byte-identical to fused7 (harness-verified). Numerics
// bit-identical: same tsplit values, same per-accumulator ks/term order.
//
// State per high-index h (bits 14-22): T[ch][b][a] (b = bits 7-13, a = bits 0-6).
//   Pass A: mid[kp=ch'*128+ka][b] = sum_{ch,a} WA[kp][ch*128+a] * T[ch][b][a]
//   Pass B: out[ch''][kb][ka]     = sum_{ch',b} WB[ch''*128+kb][ch'*128+b] * mid[ch'*128+ka][b]
// WA = (W2*W1)*W0 (fp32 on device), WB = W3, Wg = [[Ui,Ur],[Ur,-Ui]].
// 3-term bf16 split both passes (ah*bh + al*bh + ah*bl).
//
// MFMA 16x16x32 bf16 layouts (HW-verified):
//   A: m = lane&15, k = (lane>>4)*8 + j (16B/lane contiguous)
//   B: n = lane&15, k = (lane>>4)*8 + j
//   C/D: col(n) = lane&15, row(m) = (lane>>4)*4 + reg

typedef __attribute__((ext_vector_type(8))) short bf16x8;
typedef __attribute__((ext_vector_type(4))) short bf16x4;
typedef __attribute__((ext_vector_type(4))) float f32x4;

static constexpr int NSTATE = 1 << 23;

// truncation split: x ~= bf16(h) + bf16(l), rel err ~2^-16
__device__ inline void tsplit(float x, unsigned short& h, unsigned short& l) {
    unsigned int u = __float_as_uint(x);
    h = (unsigned short)(u >> 16);
    float hf = __uint_as_float(u & 0xFFFF0000u);
    l = (unsigned short)(__float_as_uint(x - hf) >> 16);
}

// RNE split (weights, prep only)
__device__ inline void rsplit(float x, unsigned short& h, unsigned short& l) {
    unsigned int u = __float_as_uint(x);
    unsigned int r = (u + 0x7FFFu + ((u >> 16) & 1u)) >> 16;
    h = (unsigned short)r;
    float hf = __uint_as_float(r << 16);
    unsigned int u2 = __float_as_uint(x - hf);
    l = (unsigned short)((u2 + 0x7FFFu + ((u2 >> 16) & 1u)) >> 16);
}

// signed block-matrix element: Wg[kp][ap], Ug -> U[g][0][0][0]
__device__ inline float wElem(const float* __restrict__ Ug, int kp, int ap) {
    const int co = kp >> 7, ci = ap >> 7;
    const float v = Ug[((co == ci) ? 16384 : 0) + (kp & 127) * 128 + (ap & 127)];
    return (co & ci) ? -v : v;
}

// frag-linear scatter offset (in shorts) for element (row i, col t) of a 256x256 W
__device__ inline int fragOff(int i, int t) {
    const int frag = (i >> 4) * 8 + (t >> 5);
    const int slot = (i & 15) + 16 * ((t >> 3) & 3);
    return frag * 512 + slot * 8 + (t & 7);
}

// LDS slot swizzle (involution per frag): spreads slot bits 4-5 into banks
__device__ inline int slotSwz(int frag, int slot) {
    return slot ^ ((slot >> 3) & 6) ^ (frag & 7);
}

// ---- single prep launch ----
// blocks 0..255:  WA row i = ((W2*W1)*W0)[i], rsplit + frag scatter
// blocks 256..511: WB row i = W3g[i], rsplit + frag scatter
__global__ __launch_bounds__(256)
void prep_all(const float* __restrict__ U,
              unsigned short* __restrict__ WAh, unsigned short* __restrict__ WAl,
              unsigned short* __restrict__ WBh, unsigned short* __restrict__ WBl) {
    __shared__ float Arow[256];
    const int t = threadIdx.x;
    if (blockIdx.x < 256) {
        const int i = blockIdx.x;
        Arow[t] = wElem(U + 2 * 32768, i, t);               // W2 row i
        __syncthreads();
        float r = 0.f;
        #pragma unroll 8
        for (int k = 0; k < 256; ++k)
            r = fmaf(Arow[k], wElem(U + 32768, k, t), r);   // (W2*W1)[i][t]
        __syncthreads();
        Arow[t] = r;
        __syncthreads();
        float s = 0.f;
        #pragma unroll 8
        for (int k = 0; k < 256; ++k)
            s = fmaf(Arow[k], wElem(U, k, t), s);           // * W0
        unsigned short h, l;
        rsplit(s, h, l);
        const int off = fragOff(i, t);
        WAh[off] = h; WAl[off] = l;
    } else {
        const int i = blockIdx.x - 256;
        unsigned short h, l;
        rsplit(wElem(U + 3 * 32768, i, t), h, l);
        const int off = fragOff(i, t);
        WBh[off] = h; WBl[off] = l;
    }
}

// ---- fused main: 1024 blocks (512 h x 2 ka-halves) x 512 threads ----
__global__ __launch_bounds__(512, 4)
void fused8(const float* __restrict__ src, float* __restrict__ dst,
            const unsigned short* __restrict__ WAh, const unsigned short* __restrict__ WAl,
            const unsigned short* __restrict__ WBh, const unsigned short* __restrict__ WBl)
{
    // 64 KB. Pass A: two 32 KB chunk buffers (16 frags h + 16 frags l each).
    // Pass B: Mh = shorts[0..16383], Ml = [16384..32767].
    __shared__ unsigned short S[32768];

    const int t    = threadIdx.x;
    const int lane = t & 63;
    const int w    = t >> 6;            // 0..7
    const int col  = lane & 15, quad = lane >> 4;

    // XCD-chunked swizzle: bijective for 1024 = 8*128; both ka-halves of an h
    // and 64 consecutive h run on the same XCD.
    const int sbid = (blockIdx.x & 7) * 128 + (blockIdx.x >> 3);
    const int hidx = sbid >> 1;
    const int ka0  = (sbid & 1) * 64;
    const size_t hbase = (size_t)hidx * 16384;

    // staging: thread t owns (b = t>>2, aLocal = (t&3)*16 .. +15) of each chunk
    const int sb = t >> 2;
    const int sa = (t & 3) * 16;

    // chunk q = (ch = q>>1, aHalf = q&1); holds ks = 2q, 2q+1
    auto ldChunk = [&](int q, float4* v) {
        const float* p = src + (size_t)(q >> 1) * NSTATE + hbase
                       + (size_t)sb * 128 + (q & 1) * 64 + sa;
        #pragma unroll
        for (int i = 0; i < 4; ++i) v[i] = *(const float4*)(p + i * 4);
    };
    auto stChunk = [&](int q, const float4* v) {
        const int bufH = (q & 1) * 16384;
        #pragma unroll
        for (int g = 0; g < 2; ++g) {
            const int aL = sa + g * 8;
            float f[8];
            *(float4*)&f[0] = v[g * 2];
            *(float4*)&f[4] = v[g * 2 + 1];
            bf16x8 hv, lv;
            #pragma unroll
            for (int i = 0; i < 8; ++i) {
                unsigned short h, l;
                tsplit(f[i], h, l);
                hv[i] = (short)h; lv[i] = (short)l;
            }
            const int frag = (sb >> 4) * 2 + (aL >> 5);     // b-tile*2 + ksc
            const int slot = (sb & 15) + 16 * ((aL & 31) >> 3);
            const int off  = bufH + frag * 512 + slotSwz(frag, slot) * 8;
            *(bf16x8*)&S[off] = hv;
            *(bf16x8*)&S[off + 8192] = lv;
        }
    };

    const int kptile = (w >> 2) * 8 + (ka0 >> 4) + (w & 3); // global kp tile

    f32x4 acc[8];
    #pragma unroll
    for (int mi = 0; mi < 8; ++mi) acc[mi] = (f32x4)0.f;

    // ---- prologue: state loads first, W preload under them, then store ----
    float4 stA[4], stB[4];
    ldChunk(0, stA);
    ldChunk(1, stB);

    bf16x8 wh[2], wl[2];
    #pragma unroll
    for (int i = 0; i < 2; ++i) {
        const int fw = (kptile * 8 + i) * 512 + lane * 8;
        wh[i] = *(const bf16x8*)(WAh + fw);
        wl[i] = *(const bf16x8*)(WAl + fw);
    }
    stChunk(0, stA);                    // waits only on stA; stB + W keep flying
    __syncthreads();                    // chunk 0 visible

    // ============ PASS A ============
    // m = b: 8 tiles, all owned by each wave. n: wave owns kp tile `kptile`.
    #pragma unroll
    for (int q = 0; q < 4; ++q) {
        const int bufH = (q & 1) * 16384;
        #pragma unroll
        for (int ksc = 0; ksc < 2; ++ksc) {
            const int ks  = q * 2 + ksc;
            const int cur = ks & 1;
            bf16x8 ah[4], al[4];
            #pragma unroll
            for (int half = 0; half < 2; ++half) {
                #pragma unroll
                for (int mi = 0; mi < 4; ++mi) {
                    const int frag = (half * 4 + mi) * 2 + ksc;
                    const int fo = bufH + frag * 512 + slotSwz(frag, lane) * 8;
                    ah[mi] = *(const bf16x8*)&S[fo];
                    al[mi] = *(const bf16x8*)&S[fo + 8192];
                }
                #pragma unroll
                for (int mi = 0; mi < 4; ++mi) {
                    f32x4& a = acc[half * 4 + mi];
                    a = __builtin_amdgcn_mfma_f32_16x16x32_bf16(ah[mi], wh[cur], a, 0, 0, 0);
                    a = __builtin_amdgcn_mfma_f32_16x16x32_bf16(al[mi], wh[cur], a, 0, 0, 0);
                    a = __builtin_amdgcn_mfma_f32_16x16x32_bf16(ah[mi], wl[cur], a, 0, 0, 0);
                }
            }
            if (ks < 6) {               // distance-2 W prefetch (after last use)
                const int fw = (kptile * 8 + ks + 2) * 512 + lane * 8;
                wh[cur] = *(const bf16x8*)(WAh + fw);
                wl[cur] = *(const bf16x8*)(WAl + fw);
            }
        }
        // pipeline: issue load q+2, then write q+1 (its regs arrived a phase ago)
        if (q == 0) { ldChunk(2, stA); stChunk(1, stB); }
        else if (q == 1) { ldChunk(3, stB); stChunk(2, stA); }
        else if (q == 2) { stChunk(3, stB); }
        __syncthreads();   // q<3: chunk q+1 visible & phase-q reads done;
                           // q==3: all A-reads done before MID alias write
    }

    // ---- pass-B W prefetch (global, no LDS hazard) issued before MID work ----
    bf16x8 wbh[2][2], wbl[2][2];
    #pragma unroll
    for (int i = 0; i < 2; ++i)
        #pragma unroll
        for (int nj = 0; nj < 2; ++nj) {
            const int fo = ((w * 2 + nj) * 8 + i) * 512 + lane * 8;
            wbh[i][nj] = *(const bf16x8*)(WBh + fo);
            wbl[i][nj] = *(const bf16x8*)(WBl + fo);
        }

    // ---- MID write (aliases chunk buffers) ----
    // element (b = mi*16 + quad*4 + r, kp-local = w*16 + col):
    //   frag2 = (w&3)*8 + (w>>2)*4 + (mi>>1); slot = col + 16*((mi*2+(quad>>1))&3);
    //   short-offset = (quad&1)*4 + r
    #pragma unroll
    for (int mi = 0; mi < 8; ++mi) {
        const int oct   = (mi * 2 + (quad >> 1)) & 3;
        const int frag2 = (w & 3) * 8 + (w >> 2) * 4 + (mi >> 1);
        const int soff  = frag2 * 512 + slotSwz(frag2, col + 16 * oct) * 8 + (quad & 1) * 4;
        unsigned short hh[4], ll[4];
        #pragma unroll
        for (int r = 0; r < 4; ++r) tsplit(acc[mi][r], hh[r], ll[r]);
        bf16x4 hv = { (short)hh[0], (short)hh[1], (short)hh[2], (short)hh[3] };
        bf16x4 lv = { (short)ll[0], (short)ll[1], (short)ll[2], (short)ll[3] };
        *(bf16x4*)&S[soff] = hv;            // Mh
        *(bf16x4*)&S[16384 + soff] = lv;    // Ml
    }
    __syncthreads();

    // ============ PASS B ============
    // m2 = ka-half: 4 tiles, all owned by each wave. n2: wave owns kp2 tiles
    // w*2, w*2+1. WB frags read once per block, dbuf distance-2.
    f32x4 acc2[4][2];
    #pragma unroll
    for (int mi = 0; mi < 4; ++mi)
        #pragma unroll
        for (int nj = 0; nj < 2; ++nj) acc2[mi][nj] = (f32x4)0.f;

    #pragma unroll
    for (int ks2 = 0; ks2 < 8; ++ks2) {
        const int cur = ks2 & 1;
        bf16x8 a2h[4], a2l[4];
        #pragma unroll
        for (int mi = 0; mi < 4; ++mi) {
            const int frag = mi * 8 + ks2;
            const int fo = frag * 512 + slotSwz(frag, lane) * 8;
            a2h[mi] = *(const bf16x8*)&S[fo];
            a2l[mi] = *(const bf16x8*)&S[16384 + fo];
        }
        #pragma unroll
        for (int nj = 0; nj < 2; ++nj)
            #pragma unroll
            for (int mi = 0; mi < 4; ++mi) {
                f32x4& a = acc2[mi][nj];
                a = __builtin_amdgcn_mfma_f32_16x16x32_bf16(a2h[mi], wbh[cur][nj], a, 0, 0, 0);
                a = __builtin_amdgcn_mfma_f32_16x16x32_bf16(a2l[mi], wbh[cur][nj], a, 0, 0, 0);
                a = __builtin_amdgcn_mfma_f32_16x16x32_bf16(a2h[mi], wbl[cur][nj], a, 0, 0, 0);
            }
        if (ks2 < 6) {                  // distance-2 W prefetch
            #pragma unroll
            for (int nj = 0; nj < 2; ++nj) {
                const int fo = ((w * 2 + nj) * 8 + ks2 + 2) * 512 + lane * 8;
                wbh[cur][nj] = *(const bf16x8*)(WBh + fo);
                wbl[cur][nj] = *(const bf16x8*)(WBl + fo);
            }
        }
    }

    // ---- epilogue: out[ch''][kb][ka0 + ka_loc], float4 over ka (coalesced) ----
    #pragma unroll
    for (int nj = 0; nj < 2; ++nj) {
        const int nt2  = w * 2 + nj;
        const int chpp = nt2 >> 3, kb = (nt2 & 7) * 16 + col;
        float* o = dst + (size_t)chpp * NSTATE + hbase + (size_t)kb * 128 + ka0;
        #pragma unroll
        for (int mi = 0; mi < 4; ++mi)
            *(float4*)(o + mi * 16 + quad * 4) = *(float4*)&acc2[mi][nj];
    }
}

extern "C" void kernel_launch(void* const* d_in, const int* in_sizes, int n_in,
                              void* d_out, int out_size, void* d_ws, size_t ws_size,
                              hipStream_t stream) {
    const float* state = (const float*)d_in[0];   // (2, 2^23)
    const float* U     = (const float*)d_in[1];   // (4, 2, 128, 128)
    float* out = (float*)d_out;

    // ws: WAh WAl WBh WBl (128 KB each, frag-linear bf16)
    unsigned short* WAh = (unsigned short*)d_ws;
    unsigned short* WAl = WAh + 65536;
    unsigned short* WBh = WAh + 2 * 65536;
    unsigned short* WBl = WAh + 3 * 65536;

    prep_all<<<512, 256, 0, stream>>>(U, WAh, WAl, WBh, WBl);
    fused8 <<<1024, 512, 0, stream>>>(state, out, WAh, WAl, WBh, WBl);
}